// Round 1
// baseline (5298.419 us; speedup 1.0000x reference)
//
#include <hip/hip_runtime.h>
#include <hip/hip_bf16.h>

#define DDIM 768
#define KCAND 32
#define SHOT 6

// ---------------- reductions ----------------
__device__ __forceinline__ float waveReduceSum(float v) {
#pragma unroll
    for (int off = 32; off; off >>= 1) v += __shfl_down(v, off, 64);
    return v;
}

// 256-thread block sum. red must be float[4]. Ends with __syncthreads().
__device__ __forceinline__ float blockSum(float v, float* red) {
    const int tid = threadIdx.x;
    const int lane = tid & 63, w = tid >> 6;
    v = waveReduceSum(v);
    if (lane == 0) red[w] = v;
    __syncthreads();
    float r = red[0] + red[1] + red[2] + red[3];
    __syncthreads();
    return r;
}

// ---------------- GEMM: C[M,768] = A[M,768] @ W[768,768] + bias ----------------
// 64x64 tile, 256 threads, 4x4 microtile, K-step 16, f32.
__global__ __launch_bounds__(256) void gemm_bias_f32(
    const float* __restrict__ A, const float* __restrict__ W,
    const float* __restrict__ bias, float* __restrict__ C, int M)
{
    __shared__ __align__(16) float As[16][64];
    __shared__ __align__(16) float Ws[16][64];
    const int tid = threadIdx.x;
    const int tx = tid & 15;          // 0..15 -> col group
    const int ty = tid >> 4;          // 0..15 -> row group
    const int bn = blockIdx.x * 64;
    const int bm = blockIdx.y * 64;

    const int ar = tid >> 2;          // 0..63 tile row for A load
    const int ak = (tid & 3) << 2;    // 0,4,8,12 k offset
    const int wk = tid >> 4;          // 0..15 k row for W load
    const int wn = (tid & 15) << 2;   // 0..60 col offset

    int arow = bm + ar; if (arow >= M) arow = M - 1;   // clamp (M is mult of 64 anyway)
    const float* aptr = A + (size_t)arow * DDIM + ak;
    const float* wptr = W + (size_t)wk * DDIM + bn + wn;

    float acc[4][4] = {};
    for (int kb = 0; kb < DDIM; kb += 16) {
        const float4 av = *(const float4*)(aptr + kb);
        const float4 wv = *(const float4*)(wptr + (size_t)kb * DDIM);
        As[ak + 0][ar] = av.x; As[ak + 1][ar] = av.y;
        As[ak + 2][ar] = av.z; As[ak + 3][ar] = av.w;
        *(float4*)&Ws[wk][wn] = wv;
        __syncthreads();
#pragma unroll
        for (int kk = 0; kk < 16; ++kk) {
            const float a0 = As[kk][(ty << 2) + 0];
            const float a1 = As[kk][(ty << 2) + 1];
            const float a2 = As[kk][(ty << 2) + 2];
            const float a3 = As[kk][(ty << 2) + 3];
            const float b0 = Ws[kk][(tx << 2) + 0];
            const float b1 = Ws[kk][(tx << 2) + 1];
            const float b2 = Ws[kk][(tx << 2) + 2];
            const float b3 = Ws[kk][(tx << 2) + 3];
            acc[0][0] += a0 * b0; acc[0][1] += a0 * b1; acc[0][2] += a0 * b2; acc[0][3] += a0 * b3;
            acc[1][0] += a1 * b0; acc[1][1] += a1 * b1; acc[1][2] += a1 * b2; acc[1][3] += a1 * b3;
            acc[2][0] += a2 * b0; acc[2][1] += a2 * b1; acc[2][2] += a2 * b2; acc[2][3] += a2 * b3;
            acc[3][0] += a3 * b0; acc[3][1] += a3 * b1; acc[3][2] += a3 * b2; acc[3][3] += a3 * b3;
        }
        __syncthreads();
    }

    const float4 bv = *(const float4*)(bias + bn + (tx << 2));
#pragma unroll
    for (int i = 0; i < 4; ++i) {
        const int row = bm + (ty << 2) + i;
        if (row < M) {
            float4 o;
            o.x = acc[i][0] + bv.x; o.y = acc[i][1] + bv.y;
            o.z = acc[i][2] + bv.z; o.w = acc[i][3] + bv.w;
            *(float4*)(C + (size_t)row * DDIM + bn + (tx << 2)) = o;
        }
    }
}

// ---------------- row-wise LayerNorm (+optional ReLU, +optional l2norm), in place ----------------
__global__ __launch_bounds__(256) void ln_kernel(
    float* __restrict__ X, const float* __restrict__ g,
    const float* __restrict__ be, int relu, int l2)
{
    __shared__ float red[4];
    float* x = X + (size_t)blockIdx.x * DDIM;
    const int tid = threadIdx.x;

    const float v0 = x[tid], v1 = x[tid + 256], v2 = x[tid + 512];
    const float mu = blockSum(v0 + v1 + v2, red) * (1.0f / 768.0f);
    const float d0 = v0 - mu, d1 = v1 - mu, d2 = v2 - mu;
    const float var = blockSum(d0 * d0 + d1 * d1 + d2 * d2, red) * (1.0f / 768.0f);
    const float rstd = 1.0f / sqrtf(var + 1e-5f);

    float y0 = d0 * rstd * g[tid]       + be[tid];
    float y1 = d1 * rstd * g[tid + 256] + be[tid + 256];
    float y2 = d2 * rstd * g[tid + 512] + be[tid + 512];
    if (relu) { y0 = fmaxf(y0, 0.f); y1 = fmaxf(y1, 0.f); y2 = fmaxf(y2, 0.f); }
    if (l2) {
        const float n2 = blockSum(y0 * y0 + y1 * y1 + y2 * y2, red);
        const float inv = 1.0f / fmaxf(sqrtf(n2), 1e-12f);
        y0 *= inv; y1 *= inv; y2 *= inv;
    }
    x[tid] = y0; x[tid + 256] = y1; x[tid + 512] = y2;
}

// ---------------- greedy 6-shot selection ----------------
__global__ __launch_bounds__(256) void select_kernel(
    const float* __restrict__ q, const float* __restrict__ c,
    float* __restrict__ logits, float* __restrict__ preds)
{
    __shared__ float cq[DDIM];
    __shared__ float scores[KCAND];
    __shared__ float red[4];
    __shared__ int s_pred;
    __shared__ unsigned s_mask;

    const int b = blockIdx.x;
    const int tid = threadIdx.x;
    const int lane = tid & 63, w = tid >> 6;
    const float* cb = c + (size_t)b * KCAND * DDIM;

    cq[tid]       = q[(size_t)b * DDIM + tid];
    cq[tid + 256] = q[(size_t)b * DDIM + tid + 256];
    cq[tid + 512] = q[(size_t)b * DDIM + tid + 512];
    if (tid == 0) s_mask = 0u;
    __syncthreads();

    for (int step = 0; step < SHOT; ++step) {
        // scores: 4 waves x 8 candidates each
#pragma unroll
        for (int j = 0; j < 8; ++j) {
            const int k = w * 8 + j;
            const float* ck = cb + (size_t)k * DDIM;
            float acc = 0.f;
#pragma unroll
            for (int i = 0; i < 12; ++i) acc += cq[lane + (i << 6)] * ck[lane + (i << 6)];
            acc = waveReduceSum(acc);
            if (lane == 0) {
                scores[k] = ((s_mask >> k) & 1u) ? -100.0f : acc / 0.1f;
            }
        }
        __syncthreads();

        if (tid < KCAND)
            logits[((size_t)b * SHOT + step) * KCAND + tid] = scores[tid];
        if (tid == 0) {
            int best = 0; float bv = scores[0];
#pragma unroll
            for (int k = 1; k < KCAND; ++k)
                if (scores[k] > bv) { bv = scores[k]; best = k; }
            s_pred = best;
            s_mask |= (1u << best);
            preds[(size_t)b * SHOT + step] = (float)best;
        }
        __syncthreads();

        const float* cp = cb + (size_t)s_pred * DDIM;
        const float nv0 = (cq[tid]       + cp[tid])       * 0.5f;
        const float nv1 = (cq[tid + 256] + cp[tid + 256]) * 0.5f;
        const float nv2 = (cq[tid + 512] + cp[tid + 512]) * 0.5f;
        const float n2 = blockSum(nv0 * nv0 + nv1 * nv1 + nv2 * nv2, red);
        const float inv = 1.0f / fmaxf(sqrtf(n2), 1e-12f);
        cq[tid] = nv0 * inv; cq[tid + 256] = nv1 * inv; cq[tid + 512] = nv2 * inv;
        __syncthreads();
    }
}

// ---------------- host ----------------
extern "C" void kernel_launch(void* const* d_in, const int* in_sizes, int n_in,
                              void* d_out, int out_size, void* d_ws, size_t ws_size,
                              hipStream_t stream)
{
    const int B = 4096;
    float* query = (float*)d_in[0];
    float* cand  = (float*)d_in[1];
    const float* qw1 = (const float*)d_in[2],  *qb1 = (const float*)d_in[3];
    const float* qg1 = (const float*)d_in[4],  *qbe1 = (const float*)d_in[5];
    const float* qw2 = (const float*)d_in[6],  *qb2 = (const float*)d_in[7];
    const float* qg2 = (const float*)d_in[8],  *qbe2 = (const float*)d_in[9];
    const float* cw1 = (const float*)d_in[10], *cb1 = (const float*)d_in[11];
    const float* cg1 = (const float*)d_in[12], *cbe1 = (const float*)d_in[13];
    const float* cw2 = (const float*)d_in[14], *cb2 = (const float*)d_in[15];
    const float* cg2 = (const float*)d_in[16], *cbe2 = (const float*)d_in[17];

    float* logits = (float*)d_out;
    float* preds  = logits + (size_t)B * SHOT * KCAND;
    float* buf = (float*)d_ws;

    // chunk candidate rows so the intermediate fits in d_ws
    size_t maxRows = ws_size / ((size_t)DDIM * sizeof(float));
    int chunk = (int)(maxRows & ~(size_t)63);
    if (chunk > 16384) chunk = 16384;
    if (chunk < 64) chunk = 64;   // (ws expected ample; guard against degenerate case)

    auto mlp = [&](float* X, int M,
                   const float* w1, const float* b1, const float* g1, const float* be1,
                   const float* w2, const float* b2, const float* g2, const float* be2) {
        for (int r0 = 0; r0 < M; r0 += chunk) {
            int rows = M - r0; if (rows > chunk) rows = chunk;
            dim3 grid(DDIM / 64, (rows + 63) / 64);
            // pre-LN1 into workspace
            gemm_bias_f32<<<grid, 256, 0, stream>>>(X + (size_t)r0 * DDIM, w1, b1, buf, rows);
            // LN + ReLU in place on workspace
            ln_kernel<<<rows, 256, 0, stream>>>(buf, g1, be1, 1, 0);
            // second GEMM, write over the (already consumed) input rows
            gemm_bias_f32<<<grid, 256, 0, stream>>>(buf, w2, b2, X + (size_t)r0 * DDIM, rows);
            // LN + l2norm in place -> final normalized embedding
            ln_kernel<<<rows, 256, 0, stream>>>(X + (size_t)r0 * DDIM, g2, be2, 0, 1);
        }
    };

    mlp(cand,  B * KCAND, cw1, cb1, cg1, cbe1, cw2, cb2, cg2, cbe2);
    mlp(query, B,         qw1, qb1, qg1, qbe1, qw2, qb2, qg2, qbe2);

    select_kernel<<<B, 256, 0, stream>>>(query, cand, logits, preds);
}